// Round 2
// baseline (12914.938 us; speedup 1.0000x reference)
//
#include <hip/hip_runtime.h>

// GRU: T=512 steps, B=64, I=H=1024. All inputs fp32 (per reference), output
// fp32: [T,B,H] per-step hidden states then [B,H] final hidden, concatenated.
//
// R2: fp32 interface (R1's NaN was fp32 data read as bf16). Weights converted
// once per call to bf16 in d_ws; x converted in-register; fp32 accumulate and
// fp32 elementwise h path; bf16 only at MFMA inputs.

typedef __bf16 bf16x8 __attribute__((ext_vector_type(8)));
typedef float  f32x4  __attribute__((ext_vector_type(4)));

#define TT 512
#define BB 64
#define HH 1024

// ---------------------------------------------------------------------------
// convert one fp32 matrix (HH*HH elems) to bf16
// ---------------------------------------------------------------------------
__global__ __launch_bounds__(256) void cvt_w(const float* __restrict__ src,
                                             __bf16* __restrict__ dst) {
    int i = (blockIdx.x * 256 + threadIdx.x) * 4;   // grid covers HH*HH/4
    f32x4 v = *(const f32x4*)(src + i);
    __bf16 o[4] = {(__bf16)v.x, (__bf16)v.y, (__bf16)v.z, (__bf16)v.w};
    *(ulong1*)(dst + i) = *(ulong1*)o;
}

// ---------------------------------------------------------------------------
// init: h_f32 / h_bf16 from input hidden state (fp32)
// ---------------------------------------------------------------------------
__global__ __launch_bounds__(256) void gru_init(const float* __restrict__ hid,
                                                float* __restrict__ h_f,
                                                __bf16* __restrict__ h_b) {
    int i = blockIdx.x * 256 + threadIdx.x;
    if (i < BB * HH) {
        float v = hid[i];
        h_f[i] = v;
        h_b[i] = (__bf16)v;
    }
}

// load 8 fp32 and pack to bf16x8
__device__ __forceinline__ bf16x8 ld_cvt8(const float* p) {
    f32x4 a = *(const f32x4*)p;
    f32x4 b = *(const f32x4*)(p + 4);
    bf16x8 r;
    r[0] = (__bf16)a.x; r[1] = (__bf16)a.y; r[2] = (__bf16)a.z; r[3] = (__bf16)a.w;
    r[4] = (__bf16)b.x; r[5] = (__bf16)b.y; r[6] = (__bf16)b.z; r[7] = (__bf16)b.w;
    return r;
}

// ---------------------------------------------------------------------------
// phase A: z = sigmoid(x_t@Wzi^T + h@Wzh^T + bzi + bzh)   -> zbuf (fp32)
//          r = sigmoid(x_t@Wri^T + h@Wrh^T + bri + brh); rh = bf16(r*h_f32)
// grid: 512 blocks x 64 threads; blocks 0..255 z-tiles, 256..511 r-tiles.
// One wave = one 16x16 output tile, K=2048 ([h ; x_t] vs [W*h ; W*i]).
// MFMA fragment maps (m89-verified): A[m=lane&15][k=(lane>>4)*8+j],
// B[col=lane&15][k same]; C/D col=lane&15, row=(lane>>4)*4+reg.
// ---------------------------------------------------------------------------
__global__ __launch_bounds__(64) void gru_zr(
    const float* __restrict__ x_t, const __bf16* __restrict__ h_b,
    const float* __restrict__ h_f,
    const __bf16* __restrict__ Wzh, const __bf16* __restrict__ Wzi,
    const float* __restrict__ bzh, const float* __restrict__ bzi,
    const __bf16* __restrict__ Wrh, const __bf16* __restrict__ Wri,
    const float* __restrict__ brh, const float* __restrict__ bri,
    float* __restrict__ zbuf, __bf16* __restrict__ rh)
{
    const int gate_r = blockIdx.x >> 8;      // 0 = z, 1 = r
    const int tile   = blockIdx.x & 255;     // 4 M-tiles x 64 N-tiles
    const int m0 = (tile & 3) << 4;
    const int n0 = (tile >> 2) << 4;
    const int lane = threadIdx.x;
    const int rc = lane & 15;
    const int kg = lane >> 4;

    const __bf16* Wh = gate_r ? Wrh : Wzh;
    const __bf16* Wi = gate_r ? Wri : Wzi;

    const __bf16* A1 = h_b + (m0 + rc) * HH + kg * 8;   // h_{t-1} (bf16)
    const __bf16* B1 = Wh  + (n0 + rc) * HH + kg * 8;
    const float*  A2 = x_t + (m0 + rc) * HH + kg * 8;   // x_t (fp32)
    const __bf16* B2 = Wi  + (n0 + rc) * HH + kg * 8;

    f32x4 acc = {0.f, 0.f, 0.f, 0.f};
    #pragma unroll 8
    for (int k = 0; k < HH; k += 32) {
        bf16x8 a = *(const bf16x8*)(A1 + k);
        bf16x8 b = *(const bf16x8*)(B1 + k);
        acc = __builtin_amdgcn_mfma_f32_16x16x32_bf16(a, b, acc, 0, 0, 0);
    }
    #pragma unroll 8
    for (int k = 0; k < HH; k += 32) {
        bf16x8 a = ld_cvt8(A2 + k);
        bf16x8 b = *(const bf16x8*)(B2 + k);
        acc = __builtin_amdgcn_mfma_f32_16x16x32_bf16(a, b, acc, 0, 0, 0);
    }

    const int n = n0 + rc;                   // C/D: col = lane&15
    const float bias = gate_r ? (brh[n] + bri[n]) : (bzh[n] + bzi[n]);
    #pragma unroll
    for (int r = 0; r < 4; ++r) {
        const int m = m0 + kg * 4 + r;       // C/D: row = (lane>>4)*4 + reg
        const int idx = m * HH + n;
        const float v = acc[r] + bias;
        const float s = 1.f / (1.f + __expf(-v));
        if (gate_r) rh[idx]   = (__bf16)(s * h_f[idx]);
        else        zbuf[idx] = s;
    }
}

// ---------------------------------------------------------------------------
// phase B: c = tanh(x_t@Wci^T + (r*h)@Wch^T + bci + bch)
//          h_new = (1-z)*h + z*c ; write h (fp32+bf16), out[t] (fp32)
// ---------------------------------------------------------------------------
__global__ __launch_bounds__(64) void gru_c(
    const float* __restrict__ x_t, const __bf16* __restrict__ rh,
    const __bf16* __restrict__ Wch, const __bf16* __restrict__ Wci,
    const float* __restrict__ bch, const float* __restrict__ bci,
    const float* __restrict__ zbuf,
    float* __restrict__ h_f, __bf16* __restrict__ h_b,
    float* __restrict__ out_t, float* __restrict__ out_tail, int last)
{
    const int tile = blockIdx.x;
    const int m0 = (tile & 3) << 4;
    const int n0 = (tile >> 2) << 4;
    const int lane = threadIdx.x;
    const int rc = lane & 15;
    const int kg = lane >> 4;

    const __bf16* A1 = rh  + (m0 + rc) * HH + kg * 8;   // r*h (bf16)
    const __bf16* B1 = Wch + (n0 + rc) * HH + kg * 8;
    const float*  A2 = x_t + (m0 + rc) * HH + kg * 8;   // x_t (fp32)
    const __bf16* B2 = Wci + (n0 + rc) * HH + kg * 8;

    f32x4 acc = {0.f, 0.f, 0.f, 0.f};
    #pragma unroll 8
    for (int k = 0; k < HH; k += 32) {
        bf16x8 a = *(const bf16x8*)(A1 + k);
        bf16x8 b = *(const bf16x8*)(B1 + k);
        acc = __builtin_amdgcn_mfma_f32_16x16x32_bf16(a, b, acc, 0, 0, 0);
    }
    #pragma unroll 8
    for (int k = 0; k < HH; k += 32) {
        bf16x8 a = ld_cvt8(A2 + k);
        bf16x8 b = *(const bf16x8*)(B2 + k);
        acc = __builtin_amdgcn_mfma_f32_16x16x32_bf16(a, b, acc, 0, 0, 0);
    }

    const int n = n0 + rc;
    const float bias = bch[n] + bci[n];
    #pragma unroll
    for (int r = 0; r < 4; ++r) {
        const int m = m0 + kg * 4 + r;
        const int idx = m * HH + n;
        const float c = tanhf(acc[r] + bias);
        const float z = zbuf[idx];
        const float hn = (1.f - z) * h_f[idx] + z * c;
        h_f[idx] = hn;
        h_b[idx] = (__bf16)hn;
        out_t[idx] = hn;
        if (last) out_tail[idx] = hn;
    }
}

// ---------------------------------------------------------------------------
extern "C" void kernel_launch(void* const* d_in, const int* in_sizes, int n_in,
                              void* d_out, int out_size, void* d_ws, size_t ws_size,
                              hipStream_t stream) {
    const float* x   = (const float*)d_in[0];
    const float* hid = (const float*)d_in[1];
    const float* Wzi = (const float*)d_in[2];
    const float* bzi = (const float*)d_in[3];
    const float* Wzh = (const float*)d_in[4];
    const float* bzh = (const float*)d_in[5];
    const float* Wri = (const float*)d_in[6];
    const float* bri = (const float*)d_in[7];
    const float* Wrh = (const float*)d_in[8];
    const float* brh = (const float*)d_in[9];
    const float* Wci = (const float*)d_in[10];
    const float* bci = (const float*)d_in[11];
    const float* Wch = (const float*)d_in[12];
    const float* bch = (const float*)d_in[13];
    float* out = (float*)d_out;

    // workspace layout (~12.75 MB)
    char* ws = (char*)d_ws;
    const size_t WSZ = (size_t)HH * HH * sizeof(__bf16);   // 2 MB per matrix
    __bf16* Wzh_b = (__bf16*)(ws + 0 * WSZ);
    __bf16* Wzi_b = (__bf16*)(ws + 1 * WSZ);
    __bf16* Wrh_b = (__bf16*)(ws + 2 * WSZ);
    __bf16* Wri_b = (__bf16*)(ws + 3 * WSZ);
    __bf16* Wch_b = (__bf16*)(ws + 4 * WSZ);
    __bf16* Wci_b = (__bf16*)(ws + 5 * WSZ);
    char* p = ws + 6 * WSZ;
    float*  zbuf = (float*)p;             p += (size_t)BB * HH * 4;  // 256 KB
    float*  h_f  = (float*)p;             p += (size_t)BB * HH * 4;  // 256 KB
    __bf16* h_b  = (__bf16*)p;            p += (size_t)BB * HH * 2;  // 128 KB
    __bf16* rh   = (__bf16*)p;                                       // 128 KB

    const int cvt_blocks = (HH * HH) / (256 * 4);   // 1024
    cvt_w<<<cvt_blocks, 256, 0, stream>>>(Wzh, Wzh_b);
    cvt_w<<<cvt_blocks, 256, 0, stream>>>(Wzi, Wzi_b);
    cvt_w<<<cvt_blocks, 256, 0, stream>>>(Wrh, Wrh_b);
    cvt_w<<<cvt_blocks, 256, 0, stream>>>(Wri, Wri_b);
    cvt_w<<<cvt_blocks, 256, 0, stream>>>(Wch, Wch_b);
    cvt_w<<<cvt_blocks, 256, 0, stream>>>(Wci, Wci_b);
    gru_init<<<256, 256, 0, stream>>>(hid, h_f, h_b);

    for (int t = 0; t < TT; ++t) {
        const float* x_t = x + (size_t)t * BB * HH;
        gru_zr<<<512, 64, 0, stream>>>(x_t, h_b, h_f,
                                       Wzh_b, Wzi_b, bzh, bzi,
                                       Wrh_b, Wri_b, brh, bri,
                                       zbuf, rh);
        gru_c<<<256, 64, 0, stream>>>(x_t, rh, Wch_b, Wci_b, bch, bci,
                                      zbuf, h_f, h_b,
                                      out + (size_t)t * BB * HH,
                                      out + (size_t)TT * BB * HH,
                                      (t == TT - 1) ? 1 : 0);
    }
}